// Round 3
// baseline (169.140 us; speedup 1.0000x reference)
//
#include <hip/hip_runtime.h>
#include <stdint.h>

// Problem constants (from reference)
#define BATCH 8192
#define FEAT 768
#define NCVX 32768            // BATCH * MULTIPLE_CONVEX
#define NOUT (BATCH + NCVX)   // 40960
#define UNSEEN 150

// Output is FLOAT32: flat [NOUT*FEAT] z_out followed by [NOUT] labels-as-f32.
// One thread per 16B output chunk = 4 f32.
#define ROW_CHUNKS (FEAT / 4)                          // 192
constexpr int COPY_CHUNKS = BATCH * ROW_CHUNKS;        // 1572864
constexpr int CVX_CHUNKS  = NCVX  * ROW_CHUNKS;        // 6291456
constexpr int LAB_CHUNKS  = NOUT / 4;                  // 10240
constexpr int TOTAL_CHUNKS = COPY_CHUNKS + CVX_CHUNKS + LAB_CHUNKS;

__global__ __launch_bounds__(256) void ConvexSampler_39006892982339_kernel(
    const float* __restrict__ z,       // f32 [BATCH, FEAT]
    const int*   __restrict__ labels,  // i32 [BATCH]
    const int*   __restrict__ idx_i,   // i32 [NCVX]
    const int*   __restrict__ idx_j,   // i32 [NCVX]
    const float* __restrict__ s,       // f32 [NCVX]
    float*       __restrict__ out)     // f32 [NOUT*FEAT + NOUT]
{
    int t = blockIdx.x * 256 + threadIdx.x;
    if (t >= TOTAL_CHUNKS) return;

    if (t < COPY_CHUNKS) {
        // straight copy z -> out[0 : BATCH*FEAT]
        ((float4*)out)[t] = ((const float4*)z)[t];
    } else if (t < COPY_CHUNKS + CVX_CHUNKS) {
        int c   = t - COPY_CHUNKS;
        int row = c / ROW_CHUNKS;
        int col = c - row * ROW_CHUNKS;          // float4 chunk within row
        float sw  = s[row];
        float sw1 = 1.0f - sw;
        const float4* ap = (const float4*)(z + (size_t)idx_i[row] * FEAT) + col;
        const float4* bp = (const float4*)(z + (size_t)idx_j[row] * FEAT) + col;
        float4 a = *ap;
        float4 b = *bp;
        float4 r;
        r.x = sw * a.x + sw1 * b.x;
        r.y = sw * a.y + sw1 * b.y;
        r.z = sw * a.z + sw1 * b.z;
        r.w = sw * a.w + sw1 * b.w;
        // convex rows land right after the copied z rows; out chunk index == t
        ((float4*)out)[t] = r;
    } else {
        // labels region: out[NOUT*FEAT + k] = (float)(k < BATCH ? labels[k] : UNSEEN)
        int c    = t - (COPY_CHUNKS + CVX_CHUNKS);
        int base = c * 4;
        float4 r;
        r.x = (float)(base + 0 < BATCH ? labels[base + 0] : UNSEEN);
        r.y = (float)(base + 1 < BATCH ? labels[base + 1] : UNSEEN);
        r.z = (float)(base + 2 < BATCH ? labels[base + 2] : UNSEEN);
        r.w = (float)(base + 3 < BATCH ? labels[base + 3] : UNSEEN);
        ((float4*)(out + (size_t)NOUT * FEAT))[c] = r;
    }
}

extern "C" void kernel_launch(void* const* d_in, const int* in_sizes, int n_in,
                              void* d_out, int out_size, void* d_ws, size_t ws_size,
                              hipStream_t stream) {
    const float* z      = (const float*)d_in[0];
    const int*   labels = (const int*)d_in[1];
    const int*   idx_i  = (const int*)d_in[2];
    const int*   idx_j  = (const int*)d_in[3];
    const float* s      = (const float*)d_in[4];
    float*       out    = (float*)d_out;

    int blocks = (TOTAL_CHUNKS + 255) / 256;
    ConvexSampler_39006892982339_kernel<<<blocks, 256, 0, stream>>>(
        z, labels, idx_i, idx_j, s, out);
}